// Round 10
// baseline (408.490 us; speedup 1.0000x reference)
//
#include <hip/hip_runtime.h>
#include <hip/hip_bf16.h>

#define ROWS 8192      // B*S
#define K2   2048      // 2*DIM
#define NCPT 2048
#define DIMD 1024

using short8 = __attribute__((ext_vector_type(8))) short;
using f32x16 = __attribute__((ext_vector_type(16))) float;

__device__ __forceinline__ unsigned short f2b(float f) {
  __hip_bfloat16 h = __float2bfloat16(f);
  return *reinterpret_cast<unsigned short*>(&h);
}
__device__ __forceinline__ float b2f(unsigned short u) {
  unsigned int x = ((unsigned int)u) << 16;
  return __uint_as_float(x);
}

__device__ __forceinline__ void store_bf16x8(unsigned short* dst, const float4& a, const float4& b) {
  union { unsigned short u[8]; uint4 q; } p;
  p.u[0]=f2b(a.x); p.u[1]=f2b(a.y); p.u[2]=f2b(a.z); p.u[3]=f2b(a.w);
  p.u[4]=f2b(b.x); p.u[5]=f2b(b.y); p.u[6]=f2b(b.z); p.u[7]=f2b(b.w);
  *reinterpret_cast<uint4*>(dst) = p.q;
}
__device__ __forceinline__ void store_bf16x4(unsigned short* dst, float a, float b, float c, float d) {
  union { unsigned short u[4]; uint2 q; } p;
  p.u[0]=f2b(a); p.u[1]=f2b(b); p.u[2]=f2b(c); p.u[3]=f2b(d);
  *reinterpret_cast<uint2*>(dst) = p.q;
}

__device__ __forceinline__ void async_lds16(const void* g, void* l) {
  __builtin_amdgcn_global_load_lds((__attribute__((address_space(1))) void*)g,
                                   (__attribute__((address_space(3))) void*)l, 16, 0, 0);
}

// ---------------- cast + row magnitude ----------------
__global__ void cast_row_mag(const float* __restrict__ src, unsigned short* __restrict__ dst,
                             float* __restrict__ mag, int ncol) {
  __shared__ float sred[4];
  int row = blockIdx.x, t = threadIdx.x;
  const float* s = src + (size_t)row * ncol;
  unsigned short* d = dst + (size_t)row * ncol;
  float ss = 0.f;
  for (int i = t * 8; i < ncol; i += 2048) {
    float4 a = *(const float4*)(s + i);
    float4 b = *(const float4*)(s + i + 4);
    ss += a.x*a.x + a.y*a.y + a.z*a.z + a.w*a.w;
    ss += b.x*b.x + b.y*b.y + b.z*b.z + b.w*b.w;
    store_bf16x8(d + i, a, b);
  }
  int lane = t & 63, w = t >> 6;
  for (int o = 32; o; o >>= 1) ss += __shfl_down(ss, o);
  if (lane == 0) sred[w] = ss;
  __syncthreads();
  if (t == 0) mag[row] = sqrtf(sred[0] + sred[1] + sred[2] + sred[3] + 1e-8f);
}

// ---------------- fused fp32 -> bf16 cast for Wl (2M) + Wo (1M) ----------------
__global__ void cast_w(const float* __restrict__ wl, const float* __restrict__ wo,
                       unsigned short* __restrict__ dst) {
  int b = blockIdx.x;
  const float* src;
  unsigned short* d;
  if (b < 1024) { src = wl + (size_t)b * 2048; d = dst + (size_t)b * 2048; }
  else {
    src = wo + (size_t)(b - 1024) * 2048;
    d = dst + (size_t)2 * 1024 * 1024 + (size_t)(b - 1024) * 2048;
  }
  int i = threadIdx.x * 8;
  float4 a = *(const float4*)(src + i);
  float4 c = *(const float4*)(src + i + 4);
  store_bf16x8(d + i, a, c);
}

// ---------------- transpose fp32 [n][n] -> bf16 [n][n]^T ----------------
__global__ void transpose_f2b(const float* __restrict__ src, unsigned short* __restrict__ dst, int n) {
  __shared__ float tile[32][33];
  int bx = blockIdx.x * 32;
  int by = blockIdx.y * 32;
  int tx = threadIdx.x & 31, ty = threadIdx.x >> 5;
  #pragma unroll
  for (int i = ty; i < 32; i += 8)
    tile[i][tx] = src[(size_t)(by + i) * n + bx + tx];
  __syncthreads();
  #pragma unroll
  for (int i = ty; i < 32; i += 8)
    dst[(size_t)(bx + i) * n + by + tx] = f2b(tile[tx][i]);
}

// ---------------- softmax over concepts (bf16 logits in, bf16 attn out) ----------------
__global__ void softmax_attn(const unsigned short* __restrict__ logit, unsigned short* __restrict__ attn) {
  __shared__ float sred[4];
  int row = blockIdx.x, t = threadIdx.x;
  int lane = t & 63, w = t >> 6;
  const unsigned short* lr = logit + (size_t)row * NCPT + t * 8;
  short8 lv = *reinterpret_cast<const short8*>(lr);
  float l[8];
  #pragma unroll
  for (int i = 0; i < 8; ++i) l[i] = b2f((unsigned short)lv[i]);
  float m = l[0];
  #pragma unroll
  for (int i = 1; i < 8; ++i) m = fmaxf(m, l[i]);
  for (int o = 32; o; o >>= 1) m = fmaxf(m, __shfl_down(m, o));
  if (lane == 0) sred[w] = m;
  __syncthreads();
  m = fmaxf(fmaxf(sred[0], sred[1]), fmaxf(sred[2], sred[3]));
  __syncthreads();
  float e[8], s = 0.f;
  #pragma unroll
  for (int i = 0; i < 8; ++i) { e[i] = expf(l[i] - m); s += e[i]; }
  for (int o = 32; o; o >>= 1) s += __shfl_down(s, o);
  if (lane == 0) sred[w] = s;
  __syncthreads();
  s = sred[0] + sred[1] + sred[2] + sred[3];
  float inv = 1.f / s;
  float4 A = make_float4(e[0]*inv, e[1]*inv, e[2]*inv, e[3]*inv);
  float4 B = make_float4(e[4]*inv, e[5]*inv, e[6]*inv, e[7]*inv);
  store_bf16x8(attn + (size_t)row * NCPT + t * 8, A, B);
}

// ---------------- per-component LayerNorm (bf16 h in); de-interleaves to bf16 rows ----------------
__global__ void phase_ln(const unsigned short* __restrict__ h, const float* __restrict__ gamma,
                         const float* __restrict__ beta, unsigned short* __restrict__ out) {
  __shared__ float4 s4[4];
  int bs = blockIdx.x, t = threadIdx.x;
  const unsigned short* hr = h + (size_t)bs * 2048 + t * 8;
  short8 hv = *reinterpret_cast<const short8*>(hr);
  float r0 = b2f((unsigned short)hv[0]), i0 = b2f((unsigned short)hv[1]);
  float r1 = b2f((unsigned short)hv[2]), i1 = b2f((unsigned short)hv[3]);
  float r2 = b2f((unsigned short)hv[4]), i2 = b2f((unsigned short)hv[5]);
  float r3 = b2f((unsigned short)hv[6]), i3 = b2f((unsigned short)hv[7]);
  float4 s;
  s.x = r0 + r1 + r2 + r3;
  s.y = r0*r0 + r1*r1 + r2*r2 + r3*r3;
  s.z = i0 + i1 + i2 + i3;
  s.w = i0*i0 + i1*i1 + i2*i2 + i3*i3;
  int lane = t & 63, w = t >> 6;
  for (int o = 32; o; o >>= 1) {
    s.x += __shfl_down(s.x, o); s.y += __shfl_down(s.y, o);
    s.z += __shfl_down(s.z, o); s.w += __shfl_down(s.w, o);
  }
  if (lane == 0) s4[w] = s;
  __syncthreads();
  float4 T = s4[0];
  #pragma unroll
  for (int i = 1; i < 4; ++i) { T.x += s4[i].x; T.y += s4[i].y; T.z += s4[i].z; T.w += s4[i].w; }
  const float invd = 1.f / 1024.f;
  float mu_r = T.x * invd, var_r = T.y * invd - mu_r * mu_r;
  float mu_i = T.z * invd, var_i = T.w * invd - mu_i * mu_i;
  float is_r = 1.f / sqrtf(var_r + 1e-5f);
  float is_i = 1.f / sqrtf(var_i + 1e-5f);
  float4 g = *(const float4*)(gamma + t * 4);
  float4 b = *(const float4*)(beta + t * 4);
  unsigned short* o0 = out + (size_t)(2 * bs) * 1024 + t * 4;
  unsigned short* o1 = out + (size_t)(2 * bs + 1) * 1024 + t * 4;
  store_bf16x4(o0, (r0-mu_r)*is_r*g.x + b.x, (r1-mu_r)*is_r*g.y + b.y,
                   (r2-mu_r)*is_r*g.z + b.z, (r3-mu_r)*is_r*g.w + b.w);
  store_bf16x4(o1, (i0-mu_i)*is_i*g.x + b.x, (i1-mu_i)*is_i*g.y + b.y,
                   (i2-mu_i)*is_i*g.z + b.z, (i3-mu_i)*is_i*g.w + b.w);
}

// =====================================================================
// 256x256 tile, BK=64, 512 threads (8 waves: 2M x 4N) — r5 schedule with
// 32x32x16 MFMA (2382 TF ceiling vs 2075; half the MFMA instructions).
// Wave tile 128x64 = 4 m-blocks(32) x 2 n-blocks(32); per phase 8 MFMA
// (2 mb x 4 k-slices).  Input frag: row=l&31, k=(l>>5)*8+j (same pattern
// family as the verified 16x16x32 reads).  C/D: col=l&31,
// row=(reg&3)+8*(reg>>2)+4*(l>>5)  [m74/m101 HW-verified].
// Staging, swizzle, vmcnt calendar identical to r5 (passing, 73 us).
// EPI: 0 = bf16 logits; 1 = bf16 h = residual + 0.1*acc;
//      2 = bias+gelu-gate+residual RMW into bf16 h; 3 = final fp32 out.
// =====================================================================
template <int EPI>
__global__ __launch_bounds__(512, 2) void gemm256(
    const unsigned short* __restrict__ A, const unsigned short* __restrict__ B,
    int M, int N, int K, void* __restrict__ Cv, const float* __restrict__ aux,
    const float* __restrict__ aux2, const unsigned short* __restrict__ auxb) {
  __shared__ char lds[131072];
  const int t = threadIdx.x;
  const int l = t & 63;
  const int wid = t >> 6;
  const int wm = wid >> 2, wn = wid & 3;

  const int nwg = gridDim.x * gridDim.y;
  int bid = blockIdx.y * gridDim.x + blockIdx.x;
  const int chunk = nwg >> 3;
  bid = (bid & 7) * chunk + (bid >> 3);
  const int row0 = (bid / gridDim.x) * 256;
  const int col0 = (bid % gridDim.x) * 256;

  const int NT = K >> 6;
  const int l31 = l & 31, l7 = l & 7, lh = l >> 5;

  f32x16 acc[4][2] = {};   // [mb 0..3][nb 0..1]; mb 0,1 = A-half0; 2,3 = A-half1
  short8 afA[2][4];        // current A half: [mb within half][ks]
  short8 bfA[4];           // B0 (n-half0), per ks
  short8 bfB[4];           // B1 (n-half1), per ks

  auto stage = [&](const unsigned short* gmat, int tileRow, int kcol, char* region) {
    const int rsub = t >> 3;
    const int csw = ((t & 7) ^ (rsub & 7)) << 3;
    const unsigned short* g0 = gmat + (size_t)(tileRow + rsub) * K + kcol + csw;
    async_lds16(g0, region + (t & ~63) * 16);
    async_lds16(g0 + (size_t)64 * K, region + 8192 + (t & ~63) * 16);
  };

  // swizzled reads: slot8 = ks*2 + (l>>5), XOR row&7 (= l&7)
  auto rdA = [&](const char* base, int mb, int ks) -> short8 {
    const int r = wm * 64 + mb * 32 + l31;
    const int sp = (((ks << 1) | lh) ^ l7) << 4;
    return *reinterpret_cast<const short8*>(base + r * 128 + sp);
  };
  auto rdB = [&](const char* base, int ks) -> short8 {
    const int r = wn * 32 + l31;
    const int sp = (((ks << 1) | lh) ^ l7) << 4;
    return *reinterpret_cast<const short8*>(base + r * 128 + sp);
  };

  // prologue: stage tiles 0 and 1 fully
  stage(A, row0,       0, lds + 0);
  stage(A, row0 + 128, 0, lds + 16384);
  stage(B, col0,       0, lds + 32768);
  stage(B, col0 + 128, 0, lds + 49152);
  if (NT > 1) {
    stage(A, row0,       64, lds + 65536 + 0);
    stage(A, row0 + 128, 64, lds + 65536 + 16384);
    stage(B, col0,       64, lds + 65536 + 32768);
    stage(B, col0 + 128, 64, lds + 65536 + 49152);
    asm volatile("s_waitcnt vmcnt(8)" ::: "memory");
  } else {
    asm volatile("s_waitcnt vmcnt(0)" ::: "memory");
  }
  __builtin_amdgcn_s_barrier();
  asm volatile("" ::: "memory");

  // pre-read B0 of tile 0
  #pragma unroll
  for (int ks = 0; ks < 4; ++ks) bfA[ks] = rdB(lds + 32768, ks);

  for (int tk = 0; tk < NT; ++tk) {
    char* bufC = lds + (tk & 1) * 65536;
    char* bufN = lds + (((tk + 1) & 1) * 65536);
    const bool pf = (tk + 2 < NT);
    const int kpf = (tk + 2) * 64;

    // ---- P0: read A-half0; MFMA Q00; read B1 ----
    #pragma unroll
    for (int mb = 0; mb < 2; ++mb)
      #pragma unroll
      for (int ks = 0; ks < 4; ++ks)
        afA[mb][ks] = rdA(bufC + 0, mb, ks);
    __builtin_amdgcn_s_setprio(1);
    #pragma unroll
    for (int ks = 0; ks < 4; ++ks)
      #pragma unroll
      for (int mb = 0; mb < 2; ++mb)
        acc[mb][0] = __builtin_amdgcn_mfma_f32_32x32x16_bf16(afA[mb][ks], bfA[ks], acc[mb][0], 0, 0, 0);
    __builtin_amdgcn_s_setprio(0);
    #pragma unroll
    for (int ks = 0; ks < 4; ++ks)
      bfB[ks] = rdB(bufC + 49152, ks);
    asm volatile("" ::: "memory");
    __builtin_amdgcn_s_barrier();
    asm volatile("" ::: "memory");

    // ---- P1: MFMA Q01; stage A0,B0(t+2) ----
    __builtin_amdgcn_s_setprio(1);
    #pragma unroll
    for (int ks = 0; ks < 4; ++ks)
      #pragma unroll
      for (int mb = 0; mb < 2; ++mb)
        acc[mb][1] = __builtin_amdgcn_mfma_f32_32x32x16_bf16(afA[mb][ks], bfB[ks], acc[mb][1], 0, 0, 0);
    __builtin_amdgcn_s_setprio(0);
    if (pf) {
      stage(A, row0, kpf, bufC + 0);
      stage(B, col0, kpf, bufC + 32768);
    }
    asm volatile("" ::: "memory");
    __builtin_amdgcn_s_barrier();
    asm volatile("" ::: "memory");

    // ---- P2: read A-half1 (overwrite afA); MFMA Q10; stage B1(t+2) ----
    #pragma unroll
    for (int mb = 0; mb < 2; ++mb)
      #pragma unroll
      for (int ks = 0; ks < 4; ++ks)
        afA[mb][ks] = rdA(bufC + 16384, mb, ks);
    __builtin_amdgcn_s_setprio(1);
    #pragma unroll
    for (int ks = 0; ks < 4; ++ks)
      #pragma unroll
      for (int mb = 0; mb < 2; ++mb)
        acc[mb + 2][0] = __builtin_amdgcn_mfma_f32_32x32x16_bf16(afA[mb][ks], bfA[ks], acc[mb + 2][0], 0, 0, 0);
    __builtin_amdgcn_s_setprio(0);
    if (pf) stage(B, col0 + 128, kpf, bufC + 49152);
    asm volatile("" ::: "memory");
    __builtin_amdgcn_s_barrier();
    asm volatile("" ::: "memory");

    // ---- P3: MFMA Q11; stage A1(t+2); read B0(t+1); vmcnt; barrier ----
    __builtin_amdgcn_s_setprio(1);
    #pragma unroll
    for (int ks = 0; ks < 4; ++ks)
      #pragma unroll
      for (int mb = 0; mb < 2; ++mb)
        acc[mb + 2][1] = __builtin_amdgcn_mfma_f32_32x32x16_bf16(afA[mb][ks], bfB[ks], acc[mb + 2][1], 0, 0, 0);
    __builtin_amdgcn_s_setprio(0);
    if (pf) stage(A, row0 + 128, kpf, bufC + 16384);
    if (tk + 1 < NT) {
      #pragma unroll
      for (int ks = 0; ks < 4; ++ks)
        bfA[ks] = rdB(bufN + 32768, ks);
    }
    if (pf) {
      asm volatile("s_waitcnt vmcnt(4)" ::: "memory");
    } else {
      asm volatile("s_waitcnt vmcnt(0)" ::: "memory");
    }
    __builtin_amdgcn_s_barrier();
    asm volatile("" ::: "memory");
  }
  asm volatile("s_waitcnt vmcnt(0)" ::: "memory");

  // ---- epilogue (32x32 C layout: col=l&31, row=(reg&3)+8*(reg>>2)+4*(l>>5)) ----
  const int rb4 = lh << 2;
  #pragma unroll
  for (int mb = 0; mb < 4; ++mb) {
    const int growb = row0 + ((mb >> 1) << 7) + wm * 64 + ((mb & 1) << 5) + rb4;
    #pragma unroll
    for (int nb = 0; nb < 2; ++nb) {
      const int gc = col0 + (nb << 7) + wn * 32 + l31;
      if constexpr (EPI == 0) {
        unsigned short* C = (unsigned short*)Cv;
        const float cm_ = aux2[gc];
        #pragma unroll
        for (int q = 0; q < 4; ++q)
          #pragma unroll
          for (int j = 0; j < 4; ++j) {
            const int r = growb + q * 8 + j;
            float v = 2.f * acc[mb][nb][q * 4 + j] / (aux[r] * cm_ + 1e-8f);
            C[(size_t)r * N + gc] = f2b(v);
          }
      } else if constexpr (EPI == 1) {
        unsigned short* C = (unsigned short*)Cv;
        #pragma unroll
        for (int q = 0; q < 4; ++q)
          #pragma unroll
          for (int j = 0; j < 4; ++j) {
            const int r = growb + q * 8 + j;
            C[(size_t)r * N + gc] = f2b(b2f(auxb[(size_t)r * N + gc]) + 0.1f * acc[mb][nb][q * 4 + j]);
          }
      } else if constexpr (EPI == 2) {
        unsigned short* C = (unsigned short*)Cv;
        const float bb = aux[gc];
        #pragma unroll
        for (int q = 0; q < 4; ++q)
          #pragma unroll
          for (int jj = 0; jj < 2; ++jj) {
            const int r = growb + q * 8 + jj * 2;   // growb multiple of 4 -> (even, odd) pair
            float re = acc[mb][nb][q * 4 + jj * 2] + bb;
            float im = acc[mb][nb][q * 4 + jj * 2 + 1] + bb;
            float g = 0.5f * re * (1.f + erff(re * 0.70710678118654752440f));
            size_t idx = (size_t)(r >> 1) * 2048 + (size_t)gc * 2;
            unsigned int hv = *(unsigned int*)(C + idx);
            float hx = b2f((unsigned short)(hv & 0xffff));
            float hy = b2f((unsigned short)(hv >> 16));
            hx += 0.1f * g * re;
            hy += 0.1f * g * im;
            unsigned int packed = (unsigned int)f2b(hx) | ((unsigned int)f2b(hy) << 16);
            *(unsigned int*)(C + idx) = packed;
          }
      } else {
        float* C = (float*)Cv;
        const float bb = aux[gc];
        #pragma unroll
        for (int q = 0; q < 4; ++q) {
          const size_t idx0 = (size_t)((growb + q * 8) >> 1) * 2048 + (size_t)gc * 2;
          float2 v01 = make_float2(acc[mb][nb][q * 4 + 0] + bb, acc[mb][nb][q * 4 + 1] + bb);
          float2 v23 = make_float2(acc[mb][nb][q * 4 + 2] + bb, acc[mb][nb][q * 4 + 3] + bb);
          *(float2*)(C + idx0) = v01;
          *(float2*)(C + idx0 + 2048) = v23;
        }
      }
    }
  }
}

extern "C" void kernel_launch(void* const* d_in, const int* in_sizes, int n_in,
                              void* d_out, int out_size, void* d_ws, size_t ws_size,
                              hipStream_t stream) {
  const float* x     = (const float*)d_in[0];
  const float* cm    = (const float*)d_in[1];
  const float* Wl    = (const float*)d_in[2];
  const float* bl    = (const float*)d_in[3];
  const float* gamma = (const float*)d_in[4];
  const float* beta  = (const float*)d_in[5];
  const float* Wo    = (const float*)d_in[6];
  const float* bo    = (const float*)d_in[7];
  const float* go    = (const float*)d_in[8];
  const float* bto   = (const float*)d_in[9];
  float* out = (float*)d_out;

  char* p = (char*)d_ws;
  unsigned short* x_bf = (unsigned short*)p; p += (size_t)ROWS * K2 * 2;
  unsigned short* c_bf = (unsigned short*)p; p += (size_t)NCPT * K2 * 2;
  unsigned short* c_T  = (unsigned short*)p; p += (size_t)K2 * NCPT * 2;
  unsigned short* w_bf = (unsigned short*)p; p += (size_t)3 * 1024 * 1024 * 2;
  float* x_mag = (float*)p; p += (size_t)ROWS * 4;
  float* c_mag = (float*)p; p += (size_t)NCPT * 4;
  unsigned short* dot_bf = (unsigned short*)p; p += (size_t)ROWS * NCPT * 2;
  unsigned short* attn   = (unsigned short*)p; p += (size_t)ROWS * NCPT * 2;
  unsigned short* h      = (unsigned short*)p; p += (size_t)ROWS * K2 * 2;   // bf16 residual stream
  unsigned short* ln_bf = attn;  // reuse after GEMM2

  // prep
  cast_row_mag<<<ROWS, 256, 0, stream>>>(x, x_bf, x_mag, K2);
  cast_row_mag<<<NCPT, 256, 0, stream>>>(cm, c_bf, c_mag, K2);
  transpose_f2b<<<dim3(64, 64), 256, 0, stream>>>(cm, c_T, 2048);
  cast_w<<<1536, 256, 0, stream>>>(Wl, Wo, w_bf);

  // concept attention
  gemm256<0><<<dim3(NCPT / 256, ROWS / 256), 512, 0, stream>>>(
      x_bf, c_bf, ROWS, NCPT, K2, dot_bf, x_mag, c_mag, nullptr);
  softmax_attn<<<ROWS, 256, 0, stream>>>(dot_bf, attn);
  gemm256<1><<<dim3(K2 / 256, ROWS / 256), 512, 0, stream>>>(
      attn, c_T, ROWS, K2, NCPT, h, nullptr, nullptr, x_bf);

  // gated FFN blocks (gelu-gate + residual fused into GEMM epilogue, bf16 h RMW)
  for (int l = 0; l < 2; ++l) {
    phase_ln<<<ROWS, 256, 0, stream>>>(h, gamma + l * 1024, beta + l * 1024, ln_bf);
    gemm256<2><<<dim3(DIMD / 256, 2 * ROWS / 256), 512, 0, stream>>>(
        ln_bf, w_bf + (size_t)l * 1024 * 1024, 2 * ROWS, DIMD, DIMD, h, bl + l * 1024, nullptr, nullptr);
  }

  // output projection
  phase_ln<<<ROWS, 256, 0, stream>>>(h, go, bto, ln_bf);
  gemm256<3><<<dim3(DIMD / 256, 2 * ROWS / 256), 512, 0, stream>>>(
      ln_bf, w_bf + 2 * 1024 * 1024, 2 * ROWS, DIMD, DIMD, out, bo, nullptr, nullptr);
}

// Round 12
// 390.375 us; speedup vs baseline: 1.0464x; 1.0464x over previous
//
#include <hip/hip_runtime.h>
#include <hip/hip_bf16.h>

#define ROWS 8192      // B*S
#define K2   2048      // 2*DIM
#define NCPT 2048
#define DIMD 1024

using short8 = __attribute__((ext_vector_type(8))) short;
using f32x4  = __attribute__((ext_vector_type(4))) float;

__device__ __forceinline__ unsigned short f2b(float f) {
  __hip_bfloat16 h = __float2bfloat16(f);
  return *reinterpret_cast<unsigned short*>(&h);
}
__device__ __forceinline__ float b2f(unsigned short u) {
  unsigned int x = ((unsigned int)u) << 16;
  return __uint_as_float(x);
}

__device__ __forceinline__ void store_bf16x8(unsigned short* dst, const float4& a, const float4& b) {
  union { unsigned short u[8]; uint4 q; } p;
  p.u[0]=f2b(a.x); p.u[1]=f2b(a.y); p.u[2]=f2b(a.z); p.u[3]=f2b(a.w);
  p.u[4]=f2b(b.x); p.u[5]=f2b(b.y); p.u[6]=f2b(b.z); p.u[7]=f2b(b.w);
  *reinterpret_cast<uint4*>(dst) = p.q;
}
__device__ __forceinline__ void store_bf16x4(unsigned short* dst, float a, float b, float c, float d) {
  union { unsigned short u[4]; uint2 q; } p;
  p.u[0]=f2b(a); p.u[1]=f2b(b); p.u[2]=f2b(c); p.u[3]=f2b(d);
  *reinterpret_cast<uint2*>(dst) = p.q;
}

__device__ __forceinline__ void async_lds16(const void* g, void* l) {
  __builtin_amdgcn_global_load_lds((__attribute__((address_space(1))) void*)g,
                                   (__attribute__((address_space(3))) void*)l, 16, 0, 0);
}

// ---------------- cast + row magnitude ----------------
__global__ void cast_row_mag(const float* __restrict__ src, unsigned short* __restrict__ dst,
                             float* __restrict__ mag, int ncol) {
  __shared__ float sred[4];
  int row = blockIdx.x, t = threadIdx.x;
  const float* s = src + (size_t)row * ncol;
  unsigned short* d = dst + (size_t)row * ncol;
  float ss = 0.f;
  for (int i = t * 8; i < ncol; i += 2048) {
    float4 a = *(const float4*)(s + i);
    float4 b = *(const float4*)(s + i + 4);
    ss += a.x*a.x + a.y*a.y + a.z*a.z + a.w*a.w;
    ss += b.x*b.x + b.y*b.y + b.z*b.z + b.w*b.w;
    store_bf16x8(d + i, a, b);
  }
  int lane = t & 63, w = t >> 6;
  for (int o = 32; o; o >>= 1) ss += __shfl_down(ss, o);
  if (lane == 0) sred[w] = ss;
  __syncthreads();
  if (t == 0) mag[row] = sqrtf(sred[0] + sred[1] + sred[2] + sred[3] + 1e-8f);
}

// ---------------- fused fp32 -> bf16 cast for Wl (2M) + Wo (1M) ----------------
__global__ void cast_w(const float* __restrict__ wl, const float* __restrict__ wo,
                       unsigned short* __restrict__ dst) {
  int b = blockIdx.x;
  const float* src;
  unsigned short* d;
  if (b < 1024) { src = wl + (size_t)b * 2048; d = dst + (size_t)b * 2048; }
  else {
    src = wo + (size_t)(b - 1024) * 2048;
    d = dst + (size_t)2 * 1024 * 1024 + (size_t)(b - 1024) * 2048;
  }
  int i = threadIdx.x * 8;
  float4 a = *(const float4*)(src + i);
  float4 c = *(const float4*)(src + i + 4);
  store_bf16x8(d + i, a, c);
}

// ---------------- transpose fp32 [n][n] -> bf16 [n][n]^T ----------------
__global__ void transpose_f2b(const float* __restrict__ src, unsigned short* __restrict__ dst, int n) {
  __shared__ float tile[32][33];
  int bx = blockIdx.x * 32;
  int by = blockIdx.y * 32;
  int tx = threadIdx.x & 31, ty = threadIdx.x >> 5;
  #pragma unroll
  for (int i = ty; i < 32; i += 8)
    tile[i][tx] = src[(size_t)(by + i) * n + bx + tx];
  __syncthreads();
  #pragma unroll
  for (int i = ty; i < 32; i += 8)
    dst[(size_t)(bx + i) * n + by + tx] = f2b(tile[tx][i]);
}

// ---------------- softmax over concepts (bf16 logits in, bf16 attn out) ----------------
__global__ void softmax_attn(const unsigned short* __restrict__ logit, unsigned short* __restrict__ attn) {
  __shared__ float sred[4];
  int row = blockIdx.x, t = threadIdx.x;
  int lane = t & 63, w = t >> 6;
  const unsigned short* lr = logit + (size_t)row * NCPT + t * 8;
  short8 lv = *reinterpret_cast<const short8*>(lr);
  float l[8];
  #pragma unroll
  for (int i = 0; i < 8; ++i) l[i] = b2f((unsigned short)lv[i]);
  float m = l[0];
  #pragma unroll
  for (int i = 1; i < 8; ++i) m = fmaxf(m, l[i]);
  for (int o = 32; o; o >>= 1) m = fmaxf(m, __shfl_down(m, o));
  if (lane == 0) sred[w] = m;
  __syncthreads();
  m = fmaxf(fmaxf(sred[0], sred[1]), fmaxf(sred[2], sred[3]));
  __syncthreads();
  float e[8], s = 0.f;
  #pragma unroll
  for (int i = 0; i < 8; ++i) { e[i] = expf(l[i] - m); s += e[i]; }
  for (int o = 32; o; o >>= 1) s += __shfl_down(s, o);
  if (lane == 0) sred[w] = s;
  __syncthreads();
  s = sred[0] + sred[1] + sred[2] + sred[3];
  float inv = 1.f / s;
  float4 A = make_float4(e[0]*inv, e[1]*inv, e[2]*inv, e[3]*inv);
  float4 B = make_float4(e[4]*inv, e[5]*inv, e[6]*inv, e[7]*inv);
  store_bf16x8(attn + (size_t)row * NCPT + t * 8, A, B);
}

// ---------------- per-component LayerNorm (bf16 h in); de-interleaves to bf16 rows ----------------
__global__ void phase_ln(const unsigned short* __restrict__ h, const float* __restrict__ gamma,
                         const float* __restrict__ beta, unsigned short* __restrict__ out) {
  __shared__ float4 s4[4];
  int bs = blockIdx.x, t = threadIdx.x;
  const unsigned short* hr = h + (size_t)bs * 2048 + t * 8;
  short8 hv = *reinterpret_cast<const short8*>(hr);
  float r0 = b2f((unsigned short)hv[0]), i0 = b2f((unsigned short)hv[1]);
  float r1 = b2f((unsigned short)hv[2]), i1 = b2f((unsigned short)hv[3]);
  float r2 = b2f((unsigned short)hv[4]), i2 = b2f((unsigned short)hv[5]);
  float r3 = b2f((unsigned short)hv[6]), i3 = b2f((unsigned short)hv[7]);
  float4 s;
  s.x = r0 + r1 + r2 + r3;
  s.y = r0*r0 + r1*r1 + r2*r2 + r3*r3;
  s.z = i0 + i1 + i2 + i3;
  s.w = i0*i0 + i1*i1 + i2*i2 + i3*i3;
  int lane = t & 63, w = t >> 6;
  for (int o = 32; o; o >>= 1) {
    s.x += __shfl_down(s.x, o); s.y += __shfl_down(s.y, o);
    s.z += __shfl_down(s.z, o); s.w += __shfl_down(s.w, o);
  }
  if (lane == 0) s4[w] = s;
  __syncthreads();
  float4 T = s4[0];
  #pragma unroll
  for (int i = 1; i < 4; ++i) { T.x += s4[i].x; T.y += s4[i].y; T.z += s4[i].z; T.w += s4[i].w; }
  const float invd = 1.f / 1024.f;
  float mu_r = T.x * invd, var_r = T.y * invd - mu_r * mu_r;
  float mu_i = T.z * invd, var_i = T.w * invd - mu_i * mu_i;
  float is_r = 1.f / sqrtf(var_r + 1e-5f);
  float is_i = 1.f / sqrtf(var_i + 1e-5f);
  float4 g = *(const float4*)(gamma + t * 4);
  float4 b = *(const float4*)(beta + t * 4);
  unsigned short* o0 = out + (size_t)(2 * bs) * 1024 + t * 4;
  unsigned short* o1 = out + (size_t)(2 * bs + 1) * 1024 + t * 4;
  store_bf16x4(o0, (r0-mu_r)*is_r*g.x + b.x, (r1-mu_r)*is_r*g.y + b.y,
                   (r2-mu_r)*is_r*g.z + b.z, (r3-mu_r)*is_r*g.w + b.w);
  store_bf16x4(o1, (i0-mu_i)*is_i*g.x + b.x, (i1-mu_i)*is_i*g.y + b.y,
                   (i2-mu_i)*is_i*g.z + b.z, (i3-mu_i)*is_i*g.w + b.w);
}

// =====================================================================
// 256x256 tile, BK=64, 512 threads (8 waves: 2M x 4N), 16x16x32 MFMA.
// r11 structure with the RACE FIXED: stages shifted one phase later so
// every stage targets a region whose last ds_read is >=2 barriers old.
//   reads : P1 a0(8)+b0(4) [lgkm throttle], P2 b1(4), P3 a1(8), P4 -
//   stages: P2 A0+B0(t+2), P3 B1(t+2), P4 A1(t+2)
//   vmcnt(6) at P4 only: retires A0(t+2) + ALL of t+1 (and older);
//   all of t+2 is retired by tk+1's vmcnt(6) before tk+2 reads it.
//   Tail (tk=NT-2): vmcnt(0).
// Phase body: {reads; stage; [throttle]; BAR; lgkmcnt(0)+sched_barrier;
//              setprio(1); 16 MFMA; setprio(0); BAR}
// EPI: 0 = bf16 logits; 1 = bf16 h = residual + 0.1*acc;
//      2 = bias+gelu-gate+residual RMW into bf16 h; 3 = final fp32 out.
// =====================================================================
template <int EPI>
__global__ __launch_bounds__(512, 2) void gemm256(
    const unsigned short* __restrict__ A, const unsigned short* __restrict__ B,
    int M, int N, int K, void* __restrict__ Cv, const float* __restrict__ aux,
    const float* __restrict__ aux2, const unsigned short* __restrict__ auxb) {
  __shared__ char lds[131072];
  const int t = threadIdx.x;
  const int l = t & 63;
  const int wid = t >> 6;
  const int wm = wid >> 2, wn = wid & 3;

  const int nwg = gridDim.x * gridDim.y;
  int bid = blockIdx.y * gridDim.x + blockIdx.x;
  const int chunk = nwg >> 3;
  bid = (bid & 7) * chunk + (bid >> 3);
  const int row0 = (bid / gridDim.x) * 256;
  const int col0 = (bid % gridDim.x) * 256;

  const int NT = K >> 6;
  const int l15 = l & 15, l7 = l & 7, lk = l >> 4;

  f32x4 acc[8][4] = {};
  short8 a_[4][2];    // current A half (A0 in P1-P2, A1 in P3-P4)
  short8 b0_[2][2];   // B0 (nh0), regs live P1->P3
  short8 b1_[2][2];   // B1 (nh1), regs live P2->P4

  auto stage = [&](const unsigned short* gmat, int tileRow, int kcol, char* region) {
    const int rsub = t >> 3;
    const int csw = ((t & 7) ^ (rsub & 7)) << 3;
    const unsigned short* g0 = gmat + (size_t)(tileRow + rsub) * K + kcol + csw;
    async_lds16(g0, region + (t & ~63) * 16);
    async_lds16(g0 + (size_t)64 * K, region + 8192 + (t & ~63) * 16);
  };

  auto rdA = [&](const char* base, int m, int kh) -> short8 {
    const int r = wm * 64 + m * 16 + l15;
    const int sp = ((((kh << 2) | lk) ^ l7) << 4);
    return *reinterpret_cast<const short8*>(base + r * 128 + sp);
  };
  auto rdB = [&](const char* base, int n, int kh) -> short8 {
    const int r = wn * 32 + n * 16 + l15;
    const int sp = ((((kh << 2) | lk) ^ l7) << 4);
    return *reinterpret_cast<const short8*>(base + r * 128 + sp);
  };

  // prologue: stage tiles 0 and 1 fully; retire tile0 (tile1 in flight)
  stage(A, row0,       0, lds + 0);
  stage(A, row0 + 128, 0, lds + 16384);
  stage(B, col0,       0, lds + 32768);
  stage(B, col0 + 128, 0, lds + 49152);
  if (NT > 1) {
    stage(A, row0,       64, lds + 65536 + 0);
    stage(A, row0 + 128, 64, lds + 65536 + 16384);
    stage(B, col0,       64, lds + 65536 + 32768);
    stage(B, col0 + 128, 64, lds + 65536 + 49152);
    asm volatile("s_waitcnt vmcnt(8)" ::: "memory");
  } else {
    asm volatile("s_waitcnt vmcnt(0)" ::: "memory");
  }
  __builtin_amdgcn_s_barrier();
  asm volatile("" ::: "memory");

  for (int tk = 0; tk < NT; ++tk) {
    char* bufC = lds + (tk & 1) * 65536;
    const bool pf = (tk + 2 < NT);
    const int kpf = (tk + 2) * 64;

    // ---- P1: read a0(8)+b0(4); throttle; Q00 ----
    #pragma unroll
    for (int m = 0; m < 4; ++m)
      #pragma unroll
      for (int kh = 0; kh < 2; ++kh)
        a_[m][kh] = rdA(bufC + 0, m, kh);
    #pragma unroll
    for (int n = 0; n < 2; ++n)
      #pragma unroll
      for (int kh = 0; kh < 2; ++kh)
        b0_[n][kh] = rdB(bufC + 32768, n, kh);
    asm volatile("s_waitcnt lgkmcnt(8)" ::: "memory");
    __builtin_amdgcn_s_barrier();
    asm volatile("s_waitcnt lgkmcnt(0)" ::: "memory");
    __builtin_amdgcn_sched_barrier(0);
    __builtin_amdgcn_s_setprio(1);
    #pragma unroll
    for (int kh = 0; kh < 2; ++kh)
      #pragma unroll
      for (int m = 0; m < 4; ++m)
        #pragma unroll
        for (int n = 0; n < 2; ++n)
          acc[m][n] = __builtin_amdgcn_mfma_f32_16x16x32_bf16(a_[m][kh], b0_[n][kh], acc[m][n], 0, 0, 0);
    __builtin_amdgcn_s_setprio(0);
    asm volatile("" ::: "memory");
    __builtin_amdgcn_s_barrier();
    asm volatile("" ::: "memory");

    // ---- P2: read b1(4); stage A0+B0(t+2); Q01 ----
    #pragma unroll
    for (int n = 0; n < 2; ++n)
      #pragma unroll
      for (int kh = 0; kh < 2; ++kh)
        b1_[n][kh] = rdB(bufC + 49152, n, kh);
    if (pf) {
      stage(A, row0, kpf, bufC + 0);
      stage(B, col0, kpf, bufC + 32768);
    }
    __builtin_amdgcn_s_barrier();
    asm volatile("s_waitcnt lgkmcnt(0)" ::: "memory");
    __builtin_amdgcn_sched_barrier(0);
    __builtin_amdgcn_s_setprio(1);
    #pragma unroll
    for (int kh = 0; kh < 2; ++kh)
      #pragma unroll
      for (int m = 0; m < 4; ++m)
        #pragma unroll
        for (int n = 0; n < 2; ++n)
          acc[m][n + 2] = __builtin_amdgcn_mfma_f32_16x16x32_bf16(a_[m][kh], b1_[n][kh], acc[m][n + 2], 0, 0, 0);
    __builtin_amdgcn_s_setprio(0);
    asm volatile("" ::: "memory");
    __builtin_amdgcn_s_barrier();
    asm volatile("" ::: "memory");

    // ---- P3: read a1(8, overwrite a_); stage B1(t+2); Q10 ----
    #pragma unroll
    for (int m = 0; m < 4; ++m)
      #pragma unroll
      for (int kh = 0; kh < 2; ++kh)
        a_[m][kh] = rdA(bufC + 16384, m, kh);
    if (pf) stage(B, col0 + 128, kpf, bufC + 49152);
    __builtin_amdgcn_s_barrier();
    asm volatile("s_waitcnt lgkmcnt(0)" ::: "memory");
    __builtin_amdgcn_sched_barrier(0);
    __builtin_amdgcn_s_setprio(1);
    #pragma unroll
    for (int kh = 0; kh < 2; ++kh)
      #pragma unroll
      for (int m = 0; m < 4; ++m)
        #pragma unroll
        for (int n = 0; n < 2; ++n)
          acc[m + 4][n] = __builtin_amdgcn_mfma_f32_16x16x32_bf16(a_[m][kh], b0_[n][kh], acc[m + 4][n], 0, 0, 0);
    __builtin_amdgcn_s_setprio(0);
    asm volatile("" ::: "memory");
    __builtin_amdgcn_s_barrier();
    asm volatile("" ::: "memory");

    // ---- P4: no reads; stage A1(t+2); vmcnt(6); Q11 ----
    if (pf) {
      stage(A, row0 + 128, kpf, bufC + 16384);
      asm volatile("s_waitcnt vmcnt(6)" ::: "memory");
    } else {
      asm volatile("s_waitcnt vmcnt(0)" ::: "memory");
    }
    __builtin_amdgcn_s_barrier();
    asm volatile("" ::: "memory");
    __builtin_amdgcn_s_setprio(1);
    #pragma unroll
    for (int kh = 0; kh < 2; ++kh)
      #pragma unroll
      for (int m = 0; m < 4; ++m)
        #pragma unroll
        for (int n = 0; n < 2; ++n)
          acc[m + 4][n + 2] = __builtin_amdgcn_mfma_f32_16x16x32_bf16(a_[m][kh], b1_[n][kh], acc[m + 4][n + 2], 0, 0, 0);
    __builtin_amdgcn_s_setprio(0);
    asm volatile("" ::: "memory");
    __builtin_amdgcn_s_barrier();
    asm volatile("" ::: "memory");
  }
  asm volatile("s_waitcnt vmcnt(0)" ::: "memory");

  // ---- epilogue ----
  const int cr = lk * 4;
  #pragma unroll
  for (int m = 0; m < 8; ++m) {
    const int gr = row0 + ((m >> 2) << 7) + wm * 64 + ((m & 3) << 4) + cr;
    #pragma unroll
    for (int n = 0; n < 4; ++n) {
      const int gc = col0 + ((n >> 1) << 7) + wn * 32 + ((n & 1) << 4) + l15;
      if constexpr (EPI == 0) {
        unsigned short* C = (unsigned short*)Cv;
        const float cm_ = aux2[gc];
        #pragma unroll
        for (int j = 0; j < 4; ++j) {
          const int r = gr + j;
          float v = 2.f * acc[m][n][j] / (aux[r] * cm_ + 1e-8f);
          C[(size_t)r * N + gc] = f2b(v);
        }
      } else if constexpr (EPI == 1) {
        unsigned short* C = (unsigned short*)Cv;
        #pragma unroll
        for (int j = 0; j < 4; ++j) {
          const int r = gr + j;
          C[(size_t)r * N + gc] = f2b(b2f(auxb[(size_t)r * N + gc]) + 0.1f * acc[m][n][j]);
        }
      } else if constexpr (EPI == 2) {
        unsigned short* C = (unsigned short*)Cv;
        const float bb = aux[gc];
        #pragma unroll
        for (int jj = 0; jj < 2; ++jj) {
          const int r = gr + jj * 2;
          float re = acc[m][n][jj * 2] + bb;
          float im = acc[m][n][jj * 2 + 1] + bb;
          float g = 0.5f * re * (1.f + erff(re * 0.70710678118654752440f));
          size_t idx = (size_t)(r >> 1) * 2048 + (size_t)gc * 2;
          unsigned int hv = *(unsigned int*)(C + idx);
          float hx = b2f((unsigned short)(hv & 0xffff));
          float hy = b2f((unsigned short)(hv >> 16));
          hx += 0.1f * g * re;
          hy += 0.1f * g * im;
          unsigned int packed = (unsigned int)f2b(hx) | ((unsigned int)f2b(hy) << 16);
          *(unsigned int*)(C + idx) = packed;
        }
      } else {
        float* C = (float*)Cv;
        const float bb = aux[gc];
        const size_t idx0 = (size_t)(gr >> 1) * 2048 + (size_t)gc * 2;
        float2 v01 = make_float2(acc[m][n][0] + bb, acc[m][n][1] + bb);
        float2 v23 = make_float2(acc[m][n][2] + bb, acc[m][n][3] + bb);
        *(float2*)(C + idx0) = v01;
        *(float2*)(C + idx0 + 2048) = v23;
      }
    }
  }
}

extern "C" void kernel_launch(void* const* d_in, const int* in_sizes, int n_in,
                              void* d_out, int out_size, void* d_ws, size_t ws_size,
                              hipStream_t stream) {
  const float* x     = (const float*)d_in[0];
  const float* cm    = (const float*)d_in[1];
  const float* Wl    = (const float*)d_in[2];
  const float* bl    = (const float*)d_in[3];
  const float* gamma = (const float*)d_in[4];
  const float* beta  = (const float*)d_in[5];
  const float* Wo    = (const float*)d_in[6];
  const float* bo    = (const float*)d_in[7];
  const float* go    = (const float*)d_in[8];
  const float* bto   = (const float*)d_in[9];
  float* out = (float*)d_out;

  char* p = (char*)d_ws;
  unsigned short* x_bf = (unsigned short*)p; p += (size_t)ROWS * K2 * 2;
  unsigned short* c_bf = (unsigned short*)p; p += (size_t)NCPT * K2 * 2;
  unsigned short* c_T  = (unsigned short*)p; p += (size_t)K2 * NCPT * 2;
  unsigned short* w_bf = (unsigned short*)p; p += (size_t)3 * 1024 * 1024 * 2;
  float* x_mag = (float*)p; p += (size_t)ROWS * 4;
  float* c_mag = (float*)p; p += (size_t)NCPT * 4;
  unsigned short* dot_bf = (unsigned short*)p; p += (size_t)ROWS * NCPT * 2;
  unsigned short* attn   = (unsigned short*)p; p += (size_t)ROWS * NCPT * 2;
  unsigned short* h      = (unsigned short*)p; p += (size_t)ROWS * K2 * 2;   // bf16 residual stream
  unsigned short* ln_bf = attn;  // reuse after GEMM2

  // prep
  cast_row_mag<<<ROWS, 256, 0, stream>>>(x, x_bf, x_mag, K2);
  cast_row_mag<<<NCPT, 256, 0, stream>>>(cm, c_bf, c_mag, K2);
  transpose_f2b<<<dim3(64, 64), 256, 0, stream>>>(cm, c_T, 2048);
  cast_w<<<1536, 256, 0, stream>>>(Wl, Wo, w_bf);

  // concept attention
  gemm256<0><<<dim3(NCPT / 256, ROWS / 256), 512, 0, stream>>>(
      x_bf, c_bf, ROWS, NCPT, K2, dot_bf, x_mag, c_mag, nullptr);
  softmax_attn<<<ROWS, 256, 0, stream>>>(dot_bf, attn);
  gemm256<1><<<dim3(K2 / 256, ROWS / 256), 512, 0, stream>>>(
      attn, c_T, ROWS, K2, NCPT, h, nullptr, nullptr, x_bf);

  // gated FFN blocks (gelu-gate + residual fused into GEMM epilogue, bf16 h RMW)
  for (int l = 0; l < 2; ++l) {
    phase_ln<<<ROWS, 256, 0, stream>>>(h, gamma + l * 1024, beta + l * 1024, ln_bf);
    gemm256<2><<<dim3(DIMD / 256, 2 * ROWS / 256), 512, 0, stream>>>(
        ln_bf, w_bf + (size_t)l * 1024 * 1024, 2 * ROWS, DIMD, DIMD, h, bl + l * 1024, nullptr, nullptr);
  }

  // output projection
  phase_ln<<<ROWS, 256, 0, stream>>>(h, go, bto, ln_bf);
  gemm256<3><<<dim3(DIMD / 256, 2 * ROWS / 256), 512, 0, stream>>>(
      ln_bf, w_bf + 2 * 1024 * 1024, 2 * ROWS, DIMD, DIMD, out, bo, nullptr, nullptr);
}

// Round 13
// 362.172 us; speedup vs baseline: 1.1279x; 1.0779x over previous
//
#include <hip/hip_runtime.h>
#include <hip/hip_bf16.h>

#define ROWS 8192      // B*S
#define K2   2048      // 2*DIM
#define NCPT 2048
#define DIMD 1024

using short8 = __attribute__((ext_vector_type(8))) short;
using f32x4  = __attribute__((ext_vector_type(4))) float;

__device__ __forceinline__ unsigned short f2b(float f) {
  __hip_bfloat16 h = __float2bfloat16(f);
  return *reinterpret_cast<unsigned short*>(&h);
}
__device__ __forceinline__ float b2f(unsigned short u) {
  unsigned int x = ((unsigned int)u) << 16;
  return __uint_as_float(x);
}

__device__ __forceinline__ void store_bf16x8(unsigned short* dst, const float4& a, const float4& b) {
  union { unsigned short u[8]; uint4 q; } p;
  p.u[0]=f2b(a.x); p.u[1]=f2b(a.y); p.u[2]=f2b(a.z); p.u[3]=f2b(a.w);
  p.u[4]=f2b(b.x); p.u[5]=f2b(b.y); p.u[6]=f2b(b.z); p.u[7]=f2b(b.w);
  *reinterpret_cast<uint4*>(dst) = p.q;
}
__device__ __forceinline__ void store_bf16x4(unsigned short* dst, float a, float b, float c, float d) {
  union { unsigned short u[4]; uint2 q; } p;
  p.u[0]=f2b(a); p.u[1]=f2b(b); p.u[2]=f2b(c); p.u[3]=f2b(d);
  *reinterpret_cast<uint2*>(dst) = p.q;
}

__device__ __forceinline__ void async_lds16(const void* g, void* l) {
  __builtin_amdgcn_global_load_lds((__attribute__((address_space(1))) void*)g,
                                   (__attribute__((address_space(3))) void*)l, 16, 0, 0);
}

// ---------------- cast + row magnitude ----------------
__global__ void cast_row_mag(const float* __restrict__ src, unsigned short* __restrict__ dst,
                             float* __restrict__ mag, int ncol) {
  __shared__ float sred[4];
  int row = blockIdx.x, t = threadIdx.x;
  const float* s = src + (size_t)row * ncol;
  unsigned short* d = dst + (size_t)row * ncol;
  float ss = 0.f;
  for (int i = t * 8; i < ncol; i += 2048) {
    float4 a = *(const float4*)(s + i);
    float4 b = *(const float4*)(s + i + 4);
    ss += a.x*a.x + a.y*a.y + a.z*a.z + a.w*a.w;
    ss += b.x*b.x + b.y*b.y + b.z*b.z + b.w*b.w;
    store_bf16x8(d + i, a, b);
  }
  int lane = t & 63, w = t >> 6;
  for (int o = 32; o; o >>= 1) ss += __shfl_down(ss, o);
  if (lane == 0) sred[w] = ss;
  __syncthreads();
  if (t == 0) mag[row] = sqrtf(sred[0] + sred[1] + sred[2] + sred[3] + 1e-8f);
}

// ---------------- fused fp32 -> bf16 cast for Wl (2M) + Wo (1M) ----------------
__global__ void cast_w(const float* __restrict__ wl, const float* __restrict__ wo,
                       unsigned short* __restrict__ dst) {
  int b = blockIdx.x;
  const float* src;
  unsigned short* d;
  if (b < 1024) { src = wl + (size_t)b * 2048; d = dst + (size_t)b * 2048; }
  else {
    src = wo + (size_t)(b - 1024) * 2048;
    d = dst + (size_t)2 * 1024 * 1024 + (size_t)(b - 1024) * 2048;
  }
  int i = threadIdx.x * 8;
  float4 a = *(const float4*)(src + i);
  float4 c = *(const float4*)(src + i + 4);
  store_bf16x8(d + i, a, c);
}

// ---------------- transpose fp32 [n][n] -> bf16 [n][n]^T ----------------
__global__ void transpose_f2b(const float* __restrict__ src, unsigned short* __restrict__ dst, int n) {
  __shared__ float tile[32][33];
  int bx = blockIdx.x * 32;
  int by = blockIdx.y * 32;
  int tx = threadIdx.x & 31, ty = threadIdx.x >> 5;
  #pragma unroll
  for (int i = ty; i < 32; i += 8)
    tile[i][tx] = src[(size_t)(by + i) * n + bx + tx];
  __syncthreads();
  #pragma unroll
  for (int i = ty; i < 32; i += 8)
    dst[(size_t)(bx + i) * n + by + tx] = f2b(tile[tx][i]);
}

// ---------------- softmax over concepts (bf16 logits in, bf16 attn out) ----------------
__global__ void softmax_attn(const unsigned short* __restrict__ logit, unsigned short* __restrict__ attn) {
  __shared__ float sred[4];
  int row = blockIdx.x, t = threadIdx.x;
  int lane = t & 63, w = t >> 6;
  const unsigned short* lr = logit + (size_t)row * NCPT + t * 8;
  short8 lv = *reinterpret_cast<const short8*>(lr);
  float l[8];
  #pragma unroll
  for (int i = 0; i < 8; ++i) l[i] = b2f((unsigned short)lv[i]);
  float m = l[0];
  #pragma unroll
  for (int i = 1; i < 8; ++i) m = fmaxf(m, l[i]);
  for (int o = 32; o; o >>= 1) m = fmaxf(m, __shfl_down(m, o));
  if (lane == 0) sred[w] = m;
  __syncthreads();
  m = fmaxf(fmaxf(sred[0], sred[1]), fmaxf(sred[2], sred[3]));
  __syncthreads();
  float e[8], s = 0.f;
  #pragma unroll
  for (int i = 0; i < 8; ++i) { e[i] = expf(l[i] - m); s += e[i]; }
  for (int o = 32; o; o >>= 1) s += __shfl_down(s, o);
  if (lane == 0) sred[w] = s;
  __syncthreads();
  s = sred[0] + sred[1] + sred[2] + sred[3];
  float inv = 1.f / s;
  float4 A = make_float4(e[0]*inv, e[1]*inv, e[2]*inv, e[3]*inv);
  float4 B = make_float4(e[4]*inv, e[5]*inv, e[6]*inv, e[7]*inv);
  store_bf16x8(attn + (size_t)row * NCPT + t * 8, A, B);
}

// ---------------- per-component LayerNorm (bf16 h in); de-interleaves to bf16 rows ----------------
__global__ void phase_ln(const unsigned short* __restrict__ h, const float* __restrict__ gamma,
                         const float* __restrict__ beta, unsigned short* __restrict__ out) {
  __shared__ float4 s4[4];
  int bs = blockIdx.x, t = threadIdx.x;
  const unsigned short* hr = h + (size_t)bs * 2048 + t * 8;
  short8 hv = *reinterpret_cast<const short8*>(hr);
  float r0 = b2f((unsigned short)hv[0]), i0 = b2f((unsigned short)hv[1]);
  float r1 = b2f((unsigned short)hv[2]), i1 = b2f((unsigned short)hv[3]);
  float r2 = b2f((unsigned short)hv[4]), i2 = b2f((unsigned short)hv[5]);
  float r3 = b2f((unsigned short)hv[6]), i3 = b2f((unsigned short)hv[7]);
  float4 s;
  s.x = r0 + r1 + r2 + r3;
  s.y = r0*r0 + r1*r1 + r2*r2 + r3*r3;
  s.z = i0 + i1 + i2 + i3;
  s.w = i0*i0 + i1*i1 + i2*i2 + i3*i3;
  int lane = t & 63, w = t >> 6;
  for (int o = 32; o; o >>= 1) {
    s.x += __shfl_down(s.x, o); s.y += __shfl_down(s.y, o);
    s.z += __shfl_down(s.z, o); s.w += __shfl_down(s.w, o);
  }
  if (lane == 0) s4[w] = s;
  __syncthreads();
  float4 T = s4[0];
  #pragma unroll
  for (int i = 1; i < 4; ++i) { T.x += s4[i].x; T.y += s4[i].y; T.z += s4[i].z; T.w += s4[i].w; }
  const float invd = 1.f / 1024.f;
  float mu_r = T.x * invd, var_r = T.y * invd - mu_r * mu_r;
  float mu_i = T.z * invd, var_i = T.w * invd - mu_i * mu_i;
  float is_r = 1.f / sqrtf(var_r + 1e-5f);
  float is_i = 1.f / sqrtf(var_i + 1e-5f);
  float4 g = *(const float4*)(gamma + t * 4);
  float4 b = *(const float4*)(beta + t * 4);
  unsigned short* o0 = out + (size_t)(2 * bs) * 1024 + t * 4;
  unsigned short* o1 = out + (size_t)(2 * bs + 1) * 1024 + t * 4;
  store_bf16x4(o0, (r0-mu_r)*is_r*g.x + b.x, (r1-mu_r)*is_r*g.y + b.y,
                   (r2-mu_r)*is_r*g.z + b.z, (r3-mu_r)*is_r*g.w + b.w);
  store_bf16x4(o1, (i0-mu_i)*is_i*g.x + b.x, (i1-mu_i)*is_i*g.y + b.y,
                   (i2-mu_i)*is_i*g.z + b.z, (i3-mu_i)*is_i*g.w + b.w);
}

// =====================================================================
// 256x256 tile, BK=64, 512 threads (8 waves: 2M x 4N) — r5 core (best
// measured): 4 phases/K-tile, one barrier per phase, MFMA overlapped with
// next-quadrant ds_reads and t+2 staging, single vmcnt(4)/K-tile at P3.
// EPI: 0 = bf16 logits (2*dot/(xm*cm+1e-8)), aux=x_mag aux2=c_mag
//      1 = bf16 h = bf16(auxb residual) + 0.1*acc
//      2 = fused bias+gelu-gate+residual RMW into bf16 h, aux=bias
//      3 = final fp32 out: interleave rows, + aux bias (paired float2 stores)
// =====================================================================
template <int EPI>
__global__ __launch_bounds__(512, 2) void gemm256(
    const unsigned short* __restrict__ A, const unsigned short* __restrict__ B,
    int M, int N, int K, void* __restrict__ Cv, const float* __restrict__ aux,
    const float* __restrict__ aux2, const unsigned short* __restrict__ auxb) {
  __shared__ char lds[131072];
  const int t = threadIdx.x;
  const int l = t & 63;
  const int wid = t >> 6;
  const int wm = wid >> 2, wn = wid & 3;

  const int nwg = gridDim.x * gridDim.y;
  int bid = blockIdx.y * gridDim.x + blockIdx.x;
  const int chunk = nwg >> 3;
  bid = (bid & 7) * chunk + (bid >> 3);
  const int row0 = (bid / gridDim.x) * 256;
  const int col0 = (bid % gridDim.x) * 256;

  const int NT = K >> 6;
  const int l15 = l & 15, l7 = l & 7, lk = l >> 4;

  f32x4 acc[8][4] = {};
  short8 afA[4][2];   // current A half (A0 in P0-P1, A1 in P2-P3)
  short8 bfA[2][2];   // B0 (nh0)
  short8 bfB[2][2];   // B1 (nh1)

  auto stage = [&](const unsigned short* gmat, int tileRow, int kcol, char* region) {
    const int rsub = t >> 3;
    const int csw = ((t & 7) ^ (rsub & 7)) << 3;
    const unsigned short* g0 = gmat + (size_t)(tileRow + rsub) * K + kcol + csw;
    async_lds16(g0, region + (t & ~63) * 16);
    async_lds16(g0 + (size_t)64 * K, region + 8192 + (t & ~63) * 16);
  };

  auto rdA = [&](const char* base, int m, int kh) -> short8 {
    const int r = wm * 64 + m * 16 + l15;
    const int sp = ((((kh << 2) | lk) ^ l7) << 4);
    return *reinterpret_cast<const short8*>(base + r * 128 + sp);
  };
  auto rdB = [&](const char* base, int n, int kh) -> short8 {
    const int r = wn * 32 + n * 16 + l15;
    const int sp = ((((kh << 2) | lk) ^ l7) << 4);
    return *reinterpret_cast<const short8*>(base + r * 128 + sp);
  };

  // prologue: stage tiles 0 and 1 fully
  stage(A, row0,       0, lds + 0);
  stage(A, row0 + 128, 0, lds + 16384);
  stage(B, col0,       0, lds + 32768);
  stage(B, col0 + 128, 0, lds + 49152);
  if (NT > 1) {
    stage(A, row0,       64, lds + 65536 + 0);
    stage(A, row0 + 128, 64, lds + 65536 + 16384);
    stage(B, col0,       64, lds + 65536 + 32768);
    stage(B, col0 + 128, 64, lds + 65536 + 49152);
    asm volatile("s_waitcnt vmcnt(8)" ::: "memory");
  } else {
    asm volatile("s_waitcnt vmcnt(0)" ::: "memory");
  }
  __builtin_amdgcn_s_barrier();
  asm volatile("" ::: "memory");

  // pre-read B0 of tile 0
  #pragma unroll
  for (int n = 0; n < 2; ++n)
    #pragma unroll
    for (int kh = 0; kh < 2; ++kh)
      bfA[n][kh] = rdB(lds + 32768, n, kh);

  for (int tk = 0; tk < NT; ++tk) {
    char* bufC = lds + (tk & 1) * 65536;
    char* bufN = lds + (((tk + 1) & 1) * 65536);
    const bool pf = (tk + 2 < NT);
    const int kpf = (tk + 2) * 64;

    // ---- P0: read A0; MFMA Q00; read B1 ----
    #pragma unroll
    for (int m = 0; m < 4; ++m)
      #pragma unroll
      for (int kh = 0; kh < 2; ++kh)
        afA[m][kh] = rdA(bufC + 0, m, kh);
    __builtin_amdgcn_s_setprio(1);
    #pragma unroll
    for (int kh = 0; kh < 2; ++kh)
      #pragma unroll
      for (int m = 0; m < 4; ++m)
        #pragma unroll
        for (int n = 0; n < 2; ++n)
          acc[m][n] = __builtin_amdgcn_mfma_f32_16x16x32_bf16(afA[m][kh], bfA[n][kh], acc[m][n], 0, 0, 0);
    __builtin_amdgcn_s_setprio(0);
    #pragma unroll
    for (int n = 0; n < 2; ++n)
      #pragma unroll
      for (int kh = 0; kh < 2; ++kh)
        bfB[n][kh] = rdB(bufC + 49152, n, kh);
    asm volatile("" ::: "memory");
    __builtin_amdgcn_s_barrier();
    asm volatile("" ::: "memory");

    // ---- P1: MFMA Q01; stage A0,B0(t+2) ----
    __builtin_amdgcn_s_setprio(1);
    #pragma unroll
    for (int kh = 0; kh < 2; ++kh)
      #pragma unroll
      for (int m = 0; m < 4; ++m)
        #pragma unroll
        for (int n = 0; n < 2; ++n)
          acc[m][n + 2] = __builtin_amdgcn_mfma_f32_16x16x32_bf16(afA[m][kh], bfB[n][kh], acc[m][n + 2], 0, 0, 0);
    __builtin_amdgcn_s_setprio(0);
    if (pf) {
      stage(A, row0, kpf, bufC + 0);
      stage(B, col0, kpf, bufC + 32768);
    }
    asm volatile("" ::: "memory");
    __builtin_amdgcn_s_barrier();
    asm volatile("" ::: "memory");

    // ---- P2: read A1 (overwrite afA); MFMA Q10; stage B1(t+2) ----
    #pragma unroll
    for (int m = 0; m < 4; ++m)
      #pragma unroll
      for (int kh = 0; kh < 2; ++kh)
        afA[m][kh] = rdA(bufC + 16384, m, kh);
    __builtin_amdgcn_s_setprio(1);
    #pragma unroll
    for (int kh = 0; kh < 2; ++kh)
      #pragma unroll
      for (int m = 0; m < 4; ++m)
        #pragma unroll
        for (int n = 0; n < 2; ++n)
          acc[m + 4][n] = __builtin_amdgcn_mfma_f32_16x16x32_bf16(afA[m][kh], bfA[n][kh], acc[m + 4][n], 0, 0, 0);
    __builtin_amdgcn_s_setprio(0);
    if (pf) stage(B, col0 + 128, kpf, bufC + 49152);
    asm volatile("" ::: "memory");
    __builtin_amdgcn_s_barrier();
    asm volatile("" ::: "memory");

    // ---- P3: MFMA Q11; stage A1(t+2); read B0(t+1); vmcnt; barrier ----
    __builtin_amdgcn_s_setprio(1);
    #pragma unroll
    for (int kh = 0; kh < 2; ++kh)
      #pragma unroll
      for (int m = 0; m < 4; ++m)
        #pragma unroll
        for (int n = 0; n < 2; ++n)
          acc[m + 4][n + 2] = __builtin_amdgcn_mfma_f32_16x16x32_bf16(afA[m][kh], bfB[n][kh], acc[m + 4][n + 2], 0, 0, 0);
    __builtin_amdgcn_s_setprio(0);
    if (pf) stage(A, row0 + 128, kpf, bufC + 16384);
    if (tk + 1 < NT) {
      #pragma unroll
      for (int n = 0; n < 2; ++n)
        #pragma unroll
        for (int kh = 0; kh < 2; ++kh)
          bfA[n][kh] = rdB(bufN + 32768, n, kh);
    }
    if (pf) {
      asm volatile("s_waitcnt vmcnt(4)" ::: "memory");
    } else {
      asm volatile("s_waitcnt vmcnt(0)" ::: "memory");
    }
    __builtin_amdgcn_s_barrier();
    asm volatile("" ::: "memory");
  }
  asm volatile("s_waitcnt vmcnt(0)" ::: "memory");

  // ---- epilogue ----
  const int cr = lk * 4;
  #pragma unroll
  for (int m = 0; m < 8; ++m) {
    const int gr = row0 + ((m >> 2) << 7) + wm * 64 + ((m & 3) << 4) + cr;
    #pragma unroll
    for (int n = 0; n < 4; ++n) {
      const int gc = col0 + ((n >> 1) << 7) + wn * 32 + ((n & 1) << 4) + l15;
      if constexpr (EPI == 0) {
        unsigned short* C = (unsigned short*)Cv;
        const float cm_ = aux2[gc];
        #pragma unroll
        for (int j = 0; j < 4; ++j) {
          const int r = gr + j;
          float v = 2.f * acc[m][n][j] / (aux[r] * cm_ + 1e-8f);
          C[(size_t)r * N + gc] = f2b(v);
        }
      } else if constexpr (EPI == 1) {
        unsigned short* C = (unsigned short*)Cv;
        #pragma unroll
        for (int j = 0; j < 4; ++j) {
          const int r = gr + j;
          C[(size_t)r * N + gc] = f2b(b2f(auxb[(size_t)r * N + gc]) + 0.1f * acc[m][n][j]);
        }
      } else if constexpr (EPI == 2) {
        unsigned short* C = (unsigned short*)Cv;
        const float bb = aux[gc];
        #pragma unroll
        for (int jj = 0; jj < 2; ++jj) {
          const int r = gr + jj * 2;
          float re = acc[m][n][jj * 2] + bb;
          float im = acc[m][n][jj * 2 + 1] + bb;
          float g = 0.5f * re * (1.f + erff(re * 0.70710678118654752440f));
          size_t idx = (size_t)(r >> 1) * 2048 + (size_t)gc * 2;
          unsigned int hv = *(unsigned int*)(C + idx);
          float hx = b2f((unsigned short)(hv & 0xffff));
          float hy = b2f((unsigned short)(hv >> 16));
          hx += 0.1f * g * re;
          hy += 0.1f * g * im;
          unsigned int packed = (unsigned int)f2b(hx) | ((unsigned int)f2b(hy) << 16);
          *(unsigned int*)(C + idx) = packed;
        }
      } else {
        // gr is a multiple of 4; j pairs (0,1) and (2,3) are the (p=0,p=1)
        // components of one (bs, dim) slot -> contiguous 8B float2 stores.
        float* C = (float*)Cv;
        const float bb = aux[gc];
        const size_t idx0 = (size_t)(gr >> 1) * 2048 + (size_t)gc * 2;
        float2 v01 = make_float2(acc[m][n][0] + bb, acc[m][n][1] + bb);
        float2 v23 = make_float2(acc[m][n][2] + bb, acc[m][n][3] + bb);
        *(float2*)(C + idx0) = v01;
        *(float2*)(C + idx0 + 2048) = v23;
      }
    }
  }
}

extern "C" void kernel_launch(void* const* d_in, const int* in_sizes, int n_in,
                              void* d_out, int out_size, void* d_ws, size_t ws_size,
                              hipStream_t stream) {
  const float* x     = (const float*)d_in[0];
  const float* cm    = (const float*)d_in[1];
  const float* Wl    = (const float*)d_in[2];
  const float* bl    = (const float*)d_in[3];
  const float* gamma = (const float*)d_in[4];
  const float* beta  = (const float*)d_in[5];
  const float* Wo    = (const float*)d_in[6];
  const float* bo    = (const float*)d_in[7];
  const float* go    = (const float*)d_in[8];
  const float* bto   = (const float*)d_in[9];
  float* out = (float*)d_out;

  char* p = (char*)d_ws;
  unsigned short* x_bf = (unsigned short*)p; p += (size_t)ROWS * K2 * 2;
  unsigned short* c_bf = (unsigned short*)p; p += (size_t)NCPT * K2 * 2;
  unsigned short* c_T  = (unsigned short*)p; p += (size_t)K2 * NCPT * 2;
  unsigned short* w_bf = (unsigned short*)p; p += (size_t)3 * 1024 * 1024 * 2;
  float* x_mag = (float*)p; p += (size_t)ROWS * 4;
  float* c_mag = (float*)p; p += (size_t)NCPT * 4;
  unsigned short* dot_bf = (unsigned short*)p; p += (size_t)ROWS * NCPT * 2;
  unsigned short* attn   = (unsigned short*)p; p += (size_t)ROWS * NCPT * 2;
  unsigned short* h      = (unsigned short*)p; p += (size_t)ROWS * K2 * 2;   // bf16 residual stream
  unsigned short* ln_bf = attn;  // reuse after GEMM2

  // prep
  cast_row_mag<<<ROWS, 256, 0, stream>>>(x, x_bf, x_mag, K2);
  cast_row_mag<<<NCPT, 256, 0, stream>>>(cm, c_bf, c_mag, K2);
  transpose_f2b<<<dim3(64, 64), 256, 0, stream>>>(cm, c_T, 2048);
  cast_w<<<1536, 256, 0, stream>>>(Wl, Wo, w_bf);

  // concept attention
  gemm256<0><<<dim3(NCPT / 256, ROWS / 256), 512, 0, stream>>>(
      x_bf, c_bf, ROWS, NCPT, K2, dot_bf, x_mag, c_mag, nullptr);
  softmax_attn<<<ROWS, 256, 0, stream>>>(dot_bf, attn);
  gemm256<1><<<dim3(K2 / 256, ROWS / 256), 512, 0, stream>>>(
      attn, c_T, ROWS, K2, NCPT, h, nullptr, nullptr, x_bf);

  // gated FFN blocks (gelu-gate + residual fused into GEMM epilogue, bf16 h RMW)
  for (int l = 0; l < 2; ++l) {
    phase_ln<<<ROWS, 256, 0, stream>>>(h, gamma + l * 1024, beta + l * 1024, ln_bf);
    gemm256<2><<<dim3(DIMD / 256, 2 * ROWS / 256), 512, 0, stream>>>(
        ln_bf, w_bf + (size_t)l * 1024 * 1024, 2 * ROWS, DIMD, DIMD, h, bl + l * 1024, nullptr, nullptr);
  }

  // output projection
  phase_ln<<<ROWS, 256, 0, stream>>>(h, go, bto, ln_bf);
  gemm256<3><<<dim3(DIMD / 256, 2 * ROWS / 256), 512, 0, stream>>>(
      ln_bf, w_bf + 2 * 1024 * 1024, 2 * ROWS, DIMD, DIMD, out, bo, nullptr, nullptr);
}